// Round 1
// baseline (386.006 us; speedup 1.0000x reference)
//
#include <hip/hip_runtime.h>

typedef __bf16 bf16x8 __attribute__((ext_vector_type(8)));
typedef __bf16 bf16x4 __attribute__((ext_vector_type(4)));
typedef float  f32x4  __attribute__((ext_vector_type(4)));

#define MFMA16(a, b, c) __builtin_amdgcn_mfma_f32_16x16x32_bf16(a, b, c, 0, 0, 0)

// ---------------- cast fp32 -> bf16 (vectorized) ----------------
__global__ __launch_bounds__(256) void cast_x_kernel(const float* __restrict__ in,
                                                     __bf16* __restrict__ out) {
  int i = blockIdx.x * 256 + threadIdx.x;
  const float4 v = ((const float4*)in)[i];
  bf16x4 o = {(__bf16)v.x, (__bf16)v.y, (__bf16)v.z, (__bf16)v.w};
  ((bf16x4*)out)[i] = o;
}

// ---------------- transpose + cast: out[n][k] = (bf16)in[k][n] ----------------
// in: rows x cols fp32 row-major; out: cols x rows bf16 row-major.
// grid: (cols/32, rows/32), block: (32, 8)
__global__ void transpose_cast_kernel(const float* __restrict__ in,
                                      __bf16* __restrict__ out,
                                      int rows, int cols) {
  __shared__ float tile[32][33];
  int tx = threadIdx.x, ty = threadIdx.y;
  int x = blockIdx.x * 32 + tx;
  int y0 = blockIdx.y * 32;
#pragma unroll
  for (int i = 0; i < 32; i += 8)
    tile[ty + i][tx] = in[(y0 + ty + i) * cols + x];
  __syncthreads();
  int ox = y0 + tx;          // output col = input row
  int oy0 = blockIdx.x * 32; // output row = input col
#pragma unroll
  for (int i = 0; i < 32; i += 8)
    out[(oy0 + ty + i) * rows + ox] = (__bf16)tile[tx][ty + i];
}

// ---------------- GEMM: C[M,N] = A[M,1024] * Bt[N,1024]^T ----------------
// 128x128 block tile, BK=32, 4 waves in 2x2, each wave 64x64 = 4x4 MFMA tiles.
// mode 0: QKV epilogue -> scatter into q[bh,n,d] (prescaled), k[bh,n,d], vt[bh,d,n]
// mode 1: out-proj epilogue -> fp32 out + bias
__global__ __launch_bounds__(256) void gemm_bt_kernel(
    const __bf16* __restrict__ A, const __bf16* __restrict__ Bt, int mode,
    __bf16* __restrict__ qo, __bf16* __restrict__ ko, __bf16* __restrict__ vo,
    float* __restrict__ outp, const float* __restrict__ bias) {
  __shared__ __bf16 As[128 * 40];
  __shared__ __bf16 Bs[128 * 40];
  const int tid = threadIdx.x;
  const int m0 = blockIdx.y * 128, n0 = blockIdx.x * 128;
  const int w = tid >> 6, lane = tid & 63;
  const int quad = lane >> 4, l15 = lane & 15;
  const int wm = (w >> 1) * 64, wn = (w & 1) * 64;
  f32x4 acc[4][4] = {};
  const int sr = tid >> 2;        // staging row 0..63 (and +64)
  const int sc = (tid & 3) * 8;   // staging col chunk
  const __bf16* ag = A + (m0 + sr) * 1024 + sc;
  const __bf16* bg = Bt + (n0 + sr) * 1024 + sc;
  for (int k0 = 0; k0 < 1024; k0 += 32) {
    bf16x8 a0 = *(const bf16x8*)(ag + k0);
    bf16x8 a1 = *(const bf16x8*)(ag + 64 * 1024 + k0);
    bf16x8 b0 = *(const bf16x8*)(bg + k0);
    bf16x8 b1 = *(const bf16x8*)(bg + 64 * 1024 + k0);
    __syncthreads();
    *(bf16x8*)(As + sr * 40 + sc) = a0;
    *(bf16x8*)(As + (sr + 64) * 40 + sc) = a1;
    *(bf16x8*)(Bs + sr * 40 + sc) = b0;
    *(bf16x8*)(Bs + (sr + 64) * 40 + sc) = b1;
    __syncthreads();
    bf16x8 af[4], bfr[4];
#pragma unroll
    for (int i = 0; i < 4; ++i)
      af[i] = *(const bf16x8*)(As + (wm + i * 16 + l15) * 40 + quad * 8);
#pragma unroll
    for (int j = 0; j < 4; ++j)
      bfr[j] = *(const bf16x8*)(Bs + (wn + j * 16 + l15) * 40 + quad * 8);
#pragma unroll
    for (int i = 0; i < 4; ++i)
#pragma unroll
      for (int j = 0; j < 4; ++j)
        acc[i][j] = MFMA16(af[i], bfr[j], acc[i][j]);
  }
  if (mode == 0) {
#pragma unroll
    for (int i = 0; i < 4; ++i) {
#pragma unroll
      for (int j = 0; j < 4; ++j) {
        int gc = n0 + wn + j * 16 + l15;
        int which = gc >> 10, rem = gc & 1023;
        int h = rem >> 6, dd = rem & 63;
#pragma unroll
        for (int r = 0; r < 4; ++r) {
          int gm = m0 + wm + i * 16 + quad * 4 + r;
          int b = gm >> 10, n = gm & 1023;
          int bh = b * 16 + h;
          float v = acc[i][j][r];
          if (which == 0)       qo[(bh * 1024 + n) * 64 + dd] = (__bf16)(v * 0.03125f);
          else if (which == 1)  ko[(bh * 1024 + n) * 64 + dd] = (__bf16)v;
          else                  vo[(bh * 64 + dd) * 1024 + n] = (__bf16)v;
        }
      }
    }
  } else {
#pragma unroll
    for (int j = 0; j < 4; ++j) {
      int gc = n0 + wn + j * 16 + l15;
      float bv = bias[gc];
#pragma unroll
      for (int i = 0; i < 4; ++i)
#pragma unroll
        for (int r = 0; r < 4; ++r) {
          int gm = m0 + wm + i * 16 + quad * 4 + r;
          outp[gm * 1024 + gc] = acc[i][j][r] + bv;
        }
    }
  }
}

// ---------------- flash attention ----------------
// grid: 2048 blocks (bh = blk>>4, qtile = blk&15), 256 threads = 4 waves.
// Each wave owns 16 Q rows; iterates K/V in 32-col tiles with online softmax.
// q,k: [bh][n][64] bf16 (q prescaled by 1/32); vt: [bh][64][n] bf16.
__global__ __launch_bounds__(256) void attn_kernel(
    const __bf16* __restrict__ q, const __bf16* __restrict__ k,
    const __bf16* __restrict__ vt, __bf16* __restrict__ ao) {
  __shared__ __bf16 Ks[32 * 72];       // [j=32][d=64] pad->72
  __shared__ __bf16 Vs[64 * 40];       // [d=64][j=32] pad->40
  __shared__ __bf16 Ps[4][16 * 40];    // per-wave P [i=16][j=32] pad->40
  const int tid = threadIdx.x;
  const int bh = blockIdx.x >> 4, qt = blockIdx.x & 15;
  const int w = tid >> 6, lane = tid & 63;
  const int quad = lane >> 4, l15 = lane & 15;
  const int qrow = qt * 64 + w * 16;
  const __bf16* qb = q + (bh * 1024 + qrow + l15) * 64;
  bf16x8 qf0 = *(const bf16x8*)(qb + quad * 8);
  bf16x8 qf1 = *(const bf16x8*)(qb + 32 + quad * 8);
  f32x4 o[4] = {};
  float m[4] = {-1e30f, -1e30f, -1e30f, -1e30f};
  float l[4] = {0.f, 0.f, 0.f, 0.f};
  const int krow = tid >> 3, kc = (tid & 7) * 8;  // K tile 32x64
  const int vrow = tid >> 2, vc = (tid & 3) * 8;  // Vt tile 64x32
  const __bf16* kg = k + (bh * 1024 + krow) * 64 + kc;
  const __bf16* vg = vt + (bh * 64 + vrow) * 1024 + vc;
  __bf16* pw = Ps[w];
  for (int j0 = 0; j0 < 1024; j0 += 32) {
    bf16x8 kv = *(const bf16x8*)(kg + j0 * 64);
    bf16x8 vv = *(const bf16x8*)(vg + j0);
    __syncthreads();
    *(bf16x8*)(Ks + krow * 72 + kc) = kv;
    *(bf16x8*)(Vs + vrow * 40 + vc) = vv;
    __syncthreads();
    // S = Q K^T  (two 16x16 j-subtiles, d = 2 x 32)
    f32x4 s0 = {}, s1 = {};
    {
      bf16x8 kf;
      kf = *(const bf16x8*)(Ks + l15 * 72 + quad * 8);             s0 = MFMA16(qf0, kf, s0);
      kf = *(const bf16x8*)(Ks + l15 * 72 + 32 + quad * 8);        s0 = MFMA16(qf1, kf, s0);
      kf = *(const bf16x8*)(Ks + (16 + l15) * 72 + quad * 8);      s1 = MFMA16(qf0, kf, s1);
      kf = *(const bf16x8*)(Ks + (16 + l15) * 72 + 32 + quad * 8); s1 = MFMA16(qf1, kf, s1);
    }
    float mx[4], alpha[4], rs[4], p0[4], p1[4];
#pragma unroll
    for (int r = 0; r < 4; ++r) mx[r] = fmaxf(s0[r], s1[r]);
#pragma unroll
    for (int off = 1; off < 16; off <<= 1)
#pragma unroll
      for (int r = 0; r < 4; ++r) mx[r] = fmaxf(mx[r], __shfl_xor(mx[r], off));
#pragma unroll
    for (int r = 0; r < 4; ++r) {
      float mn = fmaxf(m[r], mx[r]);
      alpha[r] = __expf(m[r] - mn);
      m[r] = mn;
      p0[r] = __expf(s0[r] - mn);
      p1[r] = __expf(s1[r] - mn);
      rs[r] = p0[r] + p1[r];
    }
#pragma unroll
    for (int off = 1; off < 16; off <<= 1)
#pragma unroll
      for (int r = 0; r < 4; ++r) rs[r] += __shfl_xor(rs[r], off);
#pragma unroll
    for (int r = 0; r < 4; ++r) {
      l[r] = l[r] * alpha[r] + rs[r];
#pragma unroll
      for (int d = 0; d < 4; ++d) o[d][r] *= alpha[r];
      // C-layout -> LDS (row = quad*4+r, cols l15 and 16+l15)
      pw[(quad * 4 + r) * 40 + l15] = (__bf16)p0[r];
      pw[(quad * 4 + r) * 40 + 16 + l15] = (__bf16)p1[r];
    }
    // read back P in A-operand layout; PV MFMA per 16-col d-tile
    bf16x8 pf = *(const bf16x8*)(pw + l15 * 40 + quad * 8);
#pragma unroll
    for (int d = 0; d < 4; ++d) {
      bf16x8 vf = *(const bf16x8*)(Vs + (d * 16 + l15) * 40 + quad * 8);
      o[d] = MFMA16(pf, vf, o[d]);
    }
  }
  const int b = bh >> 4, h = bh & 15;
#pragma unroll
  for (int r = 0; r < 4; ++r) {
    float inv = 1.0f / l[r];
    int row = b * 1024 + qrow + quad * 4 + r;
#pragma unroll
    for (int d = 0; d < 4; ++d)
      ao[row * 1024 + h * 64 + d * 16 + l15] = (__bf16)(o[d][r] * inv);
  }
}

// ---------------- launch ----------------
extern "C" void kernel_launch(void* const* d_in, const int* in_sizes, int n_in,
                              void* d_out, int out_size, void* d_ws, size_t ws_size,
                              hipStream_t stream) {
  const float* x = (const float*)d_in[0];      // [8192,1024]
  const float* w_qkv = (const float*)d_in[1];  // [1024,3072]
  const float* w_out = (const float*)d_in[2];  // [1024,1024]
  const float* b_out = (const float*)d_in[3];  // [1024]
  float* out = (float*)d_out;

  char* ws = (char*)d_ws;
  __bf16* xb    = (__bf16*)(ws);                 // 8192*1024 bf16 = 16 MiB
  __bf16* wqkvt = (__bf16*)(ws + 16777216);      // 3072*1024 bf16 = 6 MiB
  __bf16* woutt = (__bf16*)(ws + 23068672);      // 1024*1024 bf16 = 2 MiB
  __bf16* qw    = (__bf16*)(ws + 25165824);      // 128*1024*64 bf16
  __bf16* kw    = (__bf16*)(ws + 41943040);
  __bf16* vw    = (__bf16*)(ws + 58720256);      // end = 75497472
  __bf16* ao    = xb;  // alias: xb no longer needed after QKV GEMM

  cast_x_kernel<<<8192, 256, 0, stream>>>(x, xb);
  transpose_cast_kernel<<<dim3(96, 32), dim3(32, 8), 0, stream>>>(w_qkv, wqkvt, 1024, 3072);
  transpose_cast_kernel<<<dim3(32, 32), dim3(32, 8), 0, stream>>>(w_out, woutt, 1024, 1024);
  gemm_bt_kernel<<<dim3(24, 64), 256, 0, stream>>>(xb, wqkvt, 0, qw, kw, vw, nullptr, nullptr);
  attn_kernel<<<2048, 256, 0, stream>>>(qw, kw, vw, ao);
  gemm_bt_kernel<<<dim3(8, 64), 256, 0, stream>>>(ao, woutt, 1, nullptr, nullptr, nullptr, out, b_out);
}

// Round 2
// 355.311 us; speedup vs baseline: 1.0864x; 1.0864x over previous
//
#include <hip/hip_runtime.h>

typedef __bf16 bf16x8 __attribute__((ext_vector_type(8)));
typedef __bf16 bf16x4 __attribute__((ext_vector_type(4)));
typedef float  f32x4  __attribute__((ext_vector_type(4)));

#define MFMA16(a, b, c) __builtin_amdgcn_mfma_f32_16x16x32_bf16(a, b, c, 0, 0, 0)
// async global->LDS, 16B per lane; LDS dest = wave-uniform base + lane*16
#define GLL(gp, lp) __builtin_amdgcn_global_load_lds( \
    (__attribute__((address_space(1))) void*)(gp),    \
    (__attribute__((address_space(3))) void*)(lp), 16, 0, 0)

// ---------------- cast fp32 -> bf16 (vectorized) ----------------
__global__ __launch_bounds__(256) void cast_x_kernel(const float* __restrict__ in,
                                                     __bf16* __restrict__ out) {
  int i = blockIdx.x * 256 + threadIdx.x;
  const float4 v = ((const float4*)in)[i];
  bf16x4 o = {(__bf16)v.x, (__bf16)v.y, (__bf16)v.z, (__bf16)v.w};
  ((bf16x4*)out)[i] = o;
}

// ---------------- transpose + cast: out[n][k] = (bf16)in[k][n] ----------------
__global__ void transpose_cast_kernel(const float* __restrict__ in,
                                      __bf16* __restrict__ out,
                                      int rows, int cols) {
  __shared__ float tile[32][33];
  int tx = threadIdx.x, ty = threadIdx.y;
  int x = blockIdx.x * 32 + tx;
  int y0 = blockIdx.y * 32;
#pragma unroll
  for (int i = 0; i < 32; i += 8)
    tile[ty + i][tx] = in[(y0 + ty + i) * cols + x];
  __syncthreads();
  int ox = y0 + tx;
  int oy0 = blockIdx.x * 32;
#pragma unroll
  for (int i = 0; i < 32; i += 8)
    out[(oy0 + ty + i) * rows + ox] = (__bf16)tile[tx][ty + i];
}

// ---------------- GEMM: C[M,N] = A[M,1024] * Bt[N,1024]^T ----------------
// 128x128 tile, BK=32, m97-style global_load_lds staging (unpadded LDS).
__global__ __launch_bounds__(256) void gemm_bt_kernel(
    const __bf16* __restrict__ A, const __bf16* __restrict__ Bt, int mode,
    __bf16* __restrict__ qo, __bf16* __restrict__ ko, __bf16* __restrict__ vo,
    float* __restrict__ outp, const float* __restrict__ bias) {
  __shared__ __bf16 As[128 * 32];
  __shared__ __bf16 Bs[128 * 32];
  const int tid = threadIdx.x;
  const int m0 = blockIdx.y * 128, n0 = blockIdx.x * 128;
  const int w = tid >> 6, lane = tid & 63;
  const int quad = lane >> 4, l15 = lane & 15;
  const int wm = (w >> 1) * 64, wn = (w & 1) * 64;
  f32x4 acc[4][4] = {};
  const int sr = tid >> 2;        // 0..63: row within 64-row half
  const int sc = (tid & 3) * 8;   // k-chunk
  const __bf16* ag = A + (m0 + sr) * 1024 + sc;
  const __bf16* bg = Bt + (n0 + sr) * 1024 + sc;
  // wave-uniform LDS bases; HW appends lane*16B -> exactly As[sr*32+sc]
  __bf16* lA0 = As + w * 512;
  __bf16* lA1 = As + 2048 + w * 512;
  __bf16* lB0 = Bs + w * 512;
  __bf16* lB1 = Bs + 2048 + w * 512;
  for (int k0 = 0; k0 < 1024; k0 += 32) {
    __syncthreads();
    GLL(ag + k0, lA0);
    GLL(ag + 64 * 1024 + k0, lA1);
    GLL(bg + k0, lB0);
    GLL(bg + 64 * 1024 + k0, lB1);
    __syncthreads();  // drains vmcnt(0) -> LDS data visible
    bf16x8 af[4], bfr[4];
#pragma unroll
    for (int i = 0; i < 4; ++i)
      af[i] = *(const bf16x8*)(As + (wm + i * 16 + l15) * 32 + quad * 8);
#pragma unroll
    for (int j = 0; j < 4; ++j)
      bfr[j] = *(const bf16x8*)(Bs + (wn + j * 16 + l15) * 32 + quad * 8);
#pragma unroll
    for (int i = 0; i < 4; ++i)
#pragma unroll
      for (int j = 0; j < 4; ++j)
        acc[i][j] = MFMA16(af[i], bfr[j], acc[i][j]);
  }
  if (mode == 0) {
#pragma unroll
    for (int i = 0; i < 4; ++i) {
#pragma unroll
      for (int j = 0; j < 4; ++j) {
        int gc = n0 + wn + j * 16 + l15;
        int which = gc >> 10, rem = gc & 1023;
        int h = rem >> 6, dd = rem & 63;
#pragma unroll
        for (int r = 0; r < 4; ++r) {
          int gm = m0 + wm + i * 16 + quad * 4 + r;
          int b = gm >> 10, n = gm & 1023;
          int bh = b * 16 + h;
          float v = acc[i][j][r];
          if (which == 0)       qo[(bh * 1024 + n) * 64 + dd] = (__bf16)(v * 0.03125f);
          else if (which == 1)  ko[(bh * 1024 + n) * 64 + dd] = (__bf16)v;
          else                  vo[(bh * 64 + dd) * 1024 + n] = (__bf16)v;
        }
      }
    }
  } else {
#pragma unroll
    for (int j = 0; j < 4; ++j) {
      int gc = n0 + wn + j * 16 + l15;
      float bv = bias[gc];
#pragma unroll
      for (int i = 0; i < 4; ++i)
#pragma unroll
        for (int r = 0; r < 4; ++r) {
          int gm = m0 + wm + i * 16 + quad * 4 + r;
          outp[gm * 1024 + gc] = acc[i][j][r] + bv;
        }
    }
  }
}

// ---------------- flash attention, j-tile = 128 ----------------
// grid: 2048 blocks (bh = blk>>4, qtile = blk&15), 4 waves, 16 Q rows/wave.
// q prescaled by 1/32. k: [bh][n][64], vt: [bh][64][n].
__global__ __launch_bounds__(256) void attn_kernel(
    const __bf16* __restrict__ q, const __bf16* __restrict__ k,
    const __bf16* __restrict__ vt, __bf16* __restrict__ ao) {
  __shared__ __bf16 Ks[128 * 68];     // [j=128][d=64] pad->68 (dword-stride 34: 2-way, free)
  __shared__ __bf16 Vs[64 * 132];     // [d=64][j=128] pad->132 (dword-stride 66: 2-way, free)
  __shared__ __bf16 Ps[4][16 * 132];  // per-wave P [i=16][j=128] pad->132
  const int tid = threadIdx.x;
  const int bh = blockIdx.x >> 4, qt = blockIdx.x & 15;
  const int w = tid >> 6, lane = tid & 63;
  const int quad = lane >> 4, l15 = lane & 15;
  const int qrow = qt * 64 + w * 16;
  const __bf16* qb = q + (bh * 1024 + qrow + l15) * 64;
  bf16x8 qf0 = *(const bf16x8*)(qb + quad * 8);
  bf16x8 qf1 = *(const bf16x8*)(qb + 32 + quad * 8);
  f32x4 o[4] = {};
  float m[4] = {-1e30f, -1e30f, -1e30f, -1e30f};
  float l[4] = {0.f, 0.f, 0.f, 0.f};
  const int krow = tid >> 3, kc = (tid & 7) * 8;  // 32 rows x 64 cols per pass
  const int vrow = tid >> 2, vc = (tid & 3) * 8;  // 64 rows x 32 cols per pass
  const __bf16* kg = k + (bh * 1024 + krow) * 64 + kc;
  const __bf16* vg = vt + (bh * 64 + vrow) * 1024 + vc;
  __bf16* pw = Ps[w];
  for (int j0 = 0; j0 < 1024; j0 += 128) {
    bf16x8 kv[4], vv[4];
#pragma unroll
    for (int p = 0; p < 4; ++p) kv[p] = *(const bf16x8*)(kg + (j0 + p * 32) * 64);
#pragma unroll
    for (int p = 0; p < 4; ++p) vv[p] = *(const bf16x8*)(vg + j0 + p * 32);
    __syncthreads();
#pragma unroll
    for (int p = 0; p < 4; ++p) *(bf16x8*)(Ks + (krow + p * 32) * 68 + kc) = kv[p];
#pragma unroll
    for (int p = 0; p < 4; ++p) *(bf16x8*)(Vs + vrow * 132 + p * 32 + vc) = vv[p];
    __syncthreads();
    // S = Q K^T : 8 j-subtiles of 16, d = 2 x 32
    f32x4 s[8];
#pragma unroll
    for (int t = 0; t < 8; ++t) {
      f32x4 z = {};
      bf16x8 kf0 = *(const bf16x8*)(Ks + (t * 16 + l15) * 68 + quad * 8);
      bf16x8 kf1 = *(const bf16x8*)(Ks + (t * 16 + l15) * 68 + 32 + quad * 8);
      z = MFMA16(qf0, kf0, z);
      s[t] = MFMA16(qf1, kf1, z);
    }
    // online softmax over 128 cols at once
    float mx[4], alpha[4], rs[4];
#pragma unroll
    for (int r = 0; r < 4; ++r) {
      mx[r] = s[0][r];
#pragma unroll
      for (int t = 1; t < 8; ++t) mx[r] = fmaxf(mx[r], s[t][r]);
    }
#pragma unroll
    for (int off = 1; off < 16; off <<= 1)
#pragma unroll
      for (int r = 0; r < 4; ++r) mx[r] = fmaxf(mx[r], __shfl_xor(mx[r], off));
#pragma unroll
    for (int r = 0; r < 4; ++r) {
      float mn = fmaxf(m[r], mx[r]);
      alpha[r] = __expf(m[r] - mn);
      m[r] = mn;
      rs[r] = 0.f;
    }
#pragma unroll
    for (int t = 0; t < 8; ++t)
#pragma unroll
      for (int r = 0; r < 4; ++r) {
        float p = __expf(s[t][r] - m[r]);
        s[t][r] = p;
        rs[r] += p;
      }
#pragma unroll
    for (int off = 1; off < 16; off <<= 1)
#pragma unroll
      for (int r = 0; r < 4; ++r) rs[r] += __shfl_xor(rs[r], off);
#pragma unroll
    for (int r = 0; r < 4; ++r) {
      l[r] = l[r] * alpha[r] + rs[r];
#pragma unroll
      for (int d = 0; d < 4; ++d) o[d][r] *= alpha[r];
    }
    // P: C-layout -> LDS (per-wave region; wave-synchronous, no barrier)
#pragma unroll
    for (int t = 0; t < 8; ++t)
#pragma unroll
      for (int r = 0; r < 4; ++r)
        pw[(quad * 4 + r) * 132 + t * 16 + l15] = (__bf16)s[t][r];
    // PV: 4 k-chunks of 32 x 4 d-tiles
#pragma unroll
    for (int kk = 0; kk < 4; ++kk) {
      bf16x8 pf = *(const bf16x8*)(pw + l15 * 132 + kk * 32 + quad * 8);
#pragma unroll
      for (int d = 0; d < 4; ++d) {
        bf16x8 vf = *(const bf16x8*)(Vs + (d * 16 + l15) * 132 + kk * 32 + quad * 8);
        o[d] = MFMA16(pf, vf, o[d]);
      }
    }
  }
  const int b = bh >> 4, h = bh & 15;
#pragma unroll
  for (int r = 0; r < 4; ++r) {
    float inv = 1.0f / l[r];
    int row = b * 1024 + qrow + quad * 4 + r;
#pragma unroll
    for (int d = 0; d < 4; ++d)
      ao[row * 1024 + h * 64 + d * 16 + l15] = (__bf16)(o[d][r] * inv);
  }
}

// ---------------- launch ----------------
extern "C" void kernel_launch(void* const* d_in, const int* in_sizes, int n_in,
                              void* d_out, int out_size, void* d_ws, size_t ws_size,
                              hipStream_t stream) {
  const float* x = (const float*)d_in[0];      // [8192,1024]
  const float* w_qkv = (const float*)d_in[1];  // [1024,3072]
  const float* w_out = (const float*)d_in[2];  // [1024,1024]
  const float* b_out = (const float*)d_in[3];  // [1024]
  float* out = (float*)d_out;

  char* ws = (char*)d_ws;
  __bf16* xb    = (__bf16*)(ws);                 // 8192*1024 bf16 = 16 MiB
  __bf16* wqkvt = (__bf16*)(ws + 16777216);      // 3072*1024 bf16 = 6 MiB
  __bf16* woutt = (__bf16*)(ws + 23068672);      // 1024*1024 bf16 = 2 MiB
  __bf16* qw    = (__bf16*)(ws + 25165824);      // 128*1024*64 bf16
  __bf16* kw    = (__bf16*)(ws + 41943040);
  __bf16* vw    = (__bf16*)(ws + 58720256);      // end = 75497472
  __bf16* ao    = xb;  // alias: xb dead after QKV GEMM

  cast_x_kernel<<<8192, 256, 0, stream>>>(x, xb);
  transpose_cast_kernel<<<dim3(96, 32), dim3(32, 8), 0, stream>>>(w_qkv, wqkvt, 1024, 3072);
  transpose_cast_kernel<<<dim3(32, 32), dim3(32, 8), 0, stream>>>(w_out, woutt, 1024, 1024);
  gemm_bt_kernel<<<dim3(24, 64), 256, 0, stream>>>(xb, wqkvt, 0, qw, kw, vw, nullptr, nullptr);
  attn_kernel<<<2048, 256, 0, stream>>>(qw, kw, vw, ao);
  gemm_bt_kernel<<<dim3(8, 64), 256, 0, stream>>>(ao, woutt, 1, nullptr, nullptr, nullptr, out, b_out);
}

// Round 3
// 331.930 us; speedup vs baseline: 1.1629x; 1.0704x over previous
//
#include <hip/hip_runtime.h>

typedef __bf16 bf16x8 __attribute__((ext_vector_type(8)));
typedef __bf16 bf16x4 __attribute__((ext_vector_type(4)));
typedef float  f32x4  __attribute__((ext_vector_type(4)));

#define MFMA16(a, b, c) __builtin_amdgcn_mfma_f32_16x16x32_bf16(a, b, c, 0, 0, 0)
// async global->LDS, 16B per lane; LDS dest = wave-uniform base + lane*16
#define GLL(gp, lp) __builtin_amdgcn_global_load_lds( \
    (__attribute__((address_space(1))) void*)(gp),    \
    (__attribute__((address_space(3))) void*)(lp), 16, 0, 0)

// ---------------- cast fp32 -> bf16 (vectorized) ----------------
__global__ __launch_bounds__(256) void cast_x_kernel(const float* __restrict__ in,
                                                     __bf16* __restrict__ out) {
  int i = blockIdx.x * 256 + threadIdx.x;
  const float4 v = ((const float4*)in)[i];
  bf16x4 o = {(__bf16)v.x, (__bf16)v.y, (__bf16)v.z, (__bf16)v.w};
  ((bf16x4*)out)[i] = o;
}

// ---------------- transpose + cast: out[n][k] = (bf16)in[k][n] ----------------
__global__ void transpose_cast_kernel(const float* __restrict__ in,
                                      __bf16* __restrict__ out,
                                      int rows, int cols) {
  __shared__ float tile[32][33];
  int tx = threadIdx.x, ty = threadIdx.y;
  int x = blockIdx.x * 32 + tx;
  int y0 = blockIdx.y * 32;
#pragma unroll
  for (int i = 0; i < 32; i += 8)
    tile[ty + i][tx] = in[(y0 + ty + i) * cols + x];
  __syncthreads();
  int ox = y0 + tx;
  int oy0 = blockIdx.x * 32;
#pragma unroll
  for (int i = 0; i < 32; i += 8)
    out[(oy0 + ty + i) * rows + ox] = (__bf16)tile[tx][ty + i];
}

// ---------------- GEMM: C[M,N] = A[M,1024] * Bt[N,1024]^T ----------------
// 128x128 tile, BK=32, global_load_lds staging (unpadded LDS).
// Q prescale = SCALE * log2(e) so attention can use exp2 directly.
#define QSCALE 0.045084220027780106f
__global__ __launch_bounds__(256) void gemm_bt_kernel(
    const __bf16* __restrict__ A, const __bf16* __restrict__ Bt, int mode,
    __bf16* __restrict__ qo, __bf16* __restrict__ ko, __bf16* __restrict__ vo,
    float* __restrict__ outp, const float* __restrict__ bias) {
  __shared__ __bf16 As[128 * 32];
  __shared__ __bf16 Bs[128 * 32];
  const int tid = threadIdx.x;
  const int m0 = blockIdx.y * 128, n0 = blockIdx.x * 128;
  const int w = tid >> 6, lane = tid & 63;
  const int quad = lane >> 4, l15 = lane & 15;
  const int wm = (w >> 1) * 64, wn = (w & 1) * 64;
  f32x4 acc[4][4] = {};
  const int sr = tid >> 2;
  const int sc = (tid & 3) * 8;
  const __bf16* ag = A + (m0 + sr) * 1024 + sc;
  const __bf16* bg = Bt + (n0 + sr) * 1024 + sc;
  __bf16* lA0 = As + w * 512;
  __bf16* lA1 = As + 2048 + w * 512;
  __bf16* lB0 = Bs + w * 512;
  __bf16* lB1 = Bs + 2048 + w * 512;
  for (int k0 = 0; k0 < 1024; k0 += 32) {
    __syncthreads();
    GLL(ag + k0, lA0);
    GLL(ag + 64 * 1024 + k0, lA1);
    GLL(bg + k0, lB0);
    GLL(bg + 64 * 1024 + k0, lB1);
    __syncthreads();
    bf16x8 af[4], bfr[4];
#pragma unroll
    for (int i = 0; i < 4; ++i)
      af[i] = *(const bf16x8*)(As + (wm + i * 16 + l15) * 32 + quad * 8);
#pragma unroll
    for (int j = 0; j < 4; ++j)
      bfr[j] = *(const bf16x8*)(Bs + (wn + j * 16 + l15) * 32 + quad * 8);
#pragma unroll
    for (int i = 0; i < 4; ++i)
#pragma unroll
      for (int j = 0; j < 4; ++j)
        acc[i][j] = MFMA16(af[i], bfr[j], acc[i][j]);
  }
  if (mode == 0) {
#pragma unroll
    for (int i = 0; i < 4; ++i) {
#pragma unroll
      for (int j = 0; j < 4; ++j) {
        int gc = n0 + wn + j * 16 + l15;
        int which = gc >> 10, rem = gc & 1023;
        int h = rem >> 6, dd = rem & 63;
#pragma unroll
        for (int r = 0; r < 4; ++r) {
          int gm = m0 + wm + i * 16 + quad * 4 + r;
          int b = gm >> 10, n = gm & 1023;
          int bh = b * 16 + h;
          float v = acc[i][j][r];
          if (which == 0)       qo[(bh * 1024 + n) * 64 + dd] = (__bf16)(v * QSCALE);
          else if (which == 1)  ko[(bh * 1024 + n) * 64 + dd] = (__bf16)v;
          else                  vo[(bh * 64 + dd) * 1024 + n] = (__bf16)v;
        }
      }
    }
  } else {
#pragma unroll
    for (int j = 0; j < 4; ++j) {
      int gc = n0 + wn + j * 16 + l15;
      float bv = bias[gc];
#pragma unroll
      for (int i = 0; i < 4; ++i)
#pragma unroll
        for (int r = 0; r < 4; ++r) {
          int gm = m0 + wm + i * 16 + quad * 4 + r;
          outp[gm * 1024 + gc] = acc[i][j][r] + bv;
        }
    }
  }
}

// ---------------- attention, S^T formulation, no-max exp2 softmax ----------------
// grid: 1024 blocks (bh = blk>>3, qtile = blk&7), 4 waves, 32 Q rows/wave.
// q prescaled by SCALE*log2e. k: [bh][n][64], vt: [bh][64][n].
// LDS exactly 40960 B -> 4 blocks/CU. All buffers XOR-swizzled, unpadded.
__global__ __launch_bounds__(256, 4) void attn_kernel(
    const __bf16* __restrict__ q, const __bf16* __restrict__ k,
    const __bf16* __restrict__ vt, __bf16* __restrict__ ao) {
  __shared__ __bf16 Ks[128 * 64];    // [j][d], col granule g -> g ^ (j&7)
  __shared__ __bf16 Vs[64 * 128];    // [d][j], col granule g -> g ^ (d&15)
  __shared__ __bf16 Ps[4][32 * 32];  // per-wave P quarter [i32][j32], g -> g ^ (i&3)
  const int tid = threadIdx.x;
  const int bh = blockIdx.x >> 3, qt = blockIdx.x & 7;
  const int w = tid >> 6, lane = tid & 63;
  const int quad = lane >> 4, l15 = lane & 15;
  const int qrow = qt * 128 + w * 32;
  const __bf16* qb = q + (bh * 1024 + qrow) * 64;
  bf16x8 qf[2][2];
#pragma unroll
  for (int f = 0; f < 2; ++f) {
    qf[f][0] = *(const bf16x8*)(qb + (f * 16 + l15) * 64 + quad * 8);
    qf[f][1] = *(const bf16x8*)(qb + (f * 16 + l15) * 64 + 32 + quad * 8);
  }
  f32x4 o[2][4] = {};
  float rs0 = 0.f, rs1 = 0.f;
  // staging
  const int krow = tid >> 3, kg8 = tid & 7;
  const __bf16* kg = k + (bh * 1024 + krow) * 64 + kg8 * 8;
  const int ksw = ((kg8 ^ (krow & 7)) * 8);
  const int vrow = tid >> 2, vg4 = tid & 3;
  const __bf16* vg = vt + (bh * 64 + vrow) * 1024 + vg4 * 8;
  // kf swizzled col offsets (row&7 == l15&7 for rows t*16+l15)
  const int kfs0 = (quad ^ (l15 & 7)) * 8;
  const int kfs1 = ((4 + quad) ^ (l15 & 7)) * 8;
  __bf16* pw = Ps[w];
  const int psw = quad ^ (l15 & 3);  // pf read granule
  for (int j0 = 0; j0 < 1024; j0 += 128) {
    bf16x8 kv[4], vv[4];
#pragma unroll
    for (int p = 0; p < 4; ++p) kv[p] = *(const bf16x8*)(kg + (j0 + p * 32) * 64);
#pragma unroll
    for (int p = 0; p < 4; ++p) vv[p] = *(const bf16x8*)(vg + j0 + p * 32);
    __syncthreads();
#pragma unroll
    for (int p = 0; p < 4; ++p)
      *(bf16x8*)(Ks + (krow + p * 32) * 64 + ksw) = kv[p];
#pragma unroll
    for (int p = 0; p < 4; ++p)
      *(bf16x8*)(Vs + vrow * 128 + (((p * 4 + vg4) ^ (vrow & 15)) * 8)) = vv[p];
    __syncthreads();
    // S^T = K Q^T per 16-j tile; exp+pack immediately (keeps regs low)
    bf16x4 pk[2][8];
#pragma unroll
    for (int t = 0; t < 8; ++t) {
      const __bf16* kr = Ks + (t * 16 + l15) * 64;
      bf16x8 kf0 = *(const bf16x8*)(kr + kfs0);
      bf16x8 kf1 = *(const bf16x8*)(kr + kfs1);
      f32x4 z0 = {}, z1 = {};
      z0 = MFMA16(kf0, qf[0][0], z0);
      z0 = MFMA16(kf1, qf[0][1], z0);
      z1 = MFMA16(kf0, qf[1][0], z1);
      z1 = MFMA16(kf1, qf[1][1], z1);
      float p00 = exp2f(z0[0]), p01 = exp2f(z0[1]), p02 = exp2f(z0[2]), p03 = exp2f(z0[3]);
      float p10 = exp2f(z1[0]), p11 = exp2f(z1[1]), p12 = exp2f(z1[2]), p13 = exp2f(z1[3]);
      rs0 += (p00 + p01) + (p02 + p03);
      rs1 += (p10 + p11) + (p12 + p13);
      pk[0][t] = (bf16x4){(__bf16)p00, (__bf16)p01, (__bf16)p02, (__bf16)p03};
      pk[1][t] = (bf16x4){(__bf16)p10, (__bf16)p11, (__bf16)p12, (__bf16)p13};
    }
    // PV in j-quarters of 32 through the per-wave P buffer (wave-sync, no barrier)
#pragma unroll
    for (int Q = 0; Q < 4; ++Q) {
#pragma unroll
      for (int f = 0; f < 2; ++f)
#pragma unroll
        for (int tl = 0; tl < 2; ++tl) {
          int g = (2 * tl + (quad >> 1)) ^ (l15 & 3);
          *(bf16x4*)(pw + (f * 16 + l15) * 32 + g * 8 + (quad & 1) * 4) = pk[f][2 * Q + tl];
        }
      bf16x8 pf0 = *(const bf16x8*)(pw + l15 * 32 + psw * 8);
      bf16x8 pf1 = *(const bf16x8*)(pw + (16 + l15) * 32 + psw * 8);
#pragma unroll
      for (int dt = 0; dt < 4; ++dt) {
        bf16x8 vf = *(const bf16x8*)(Vs + (dt * 16 + l15) * 128 + (((Q * 4 + quad) ^ l15) * 8));
        o[0][dt] = MFMA16(pf0, vf, o[0][dt]);
        o[1][dt] = MFMA16(pf1, vf, o[1][dt]);
      }
    }
  }
  // row sums: reduce over quads once
  rs0 += __shfl_xor(rs0, 16); rs0 += __shfl_xor(rs0, 32);
  rs1 += __shfl_xor(rs1, 16); rs1 += __shfl_xor(rs1, 32);
  const int b = bh >> 4, h = bh & 15;
  const int qbase = quad << 4;
#pragma unroll
  for (int r = 0; r < 4; ++r) {
    int src = qbase | (quad * 4 + r);
    float inv0 = 1.0f / __shfl(rs0, src);
    float inv1 = 1.0f / __shfl(rs1, src);
    long row0 = b * 1024 + qrow + quad * 4 + r;
    long row1 = row0 + 16;
#pragma unroll
    for (int dt = 0; dt < 4; ++dt) {
      ao[row0 * 1024 + h * 64 + dt * 16 + l15] = (__bf16)(o[0][dt][r] * inv0);
      ao[row1 * 1024 + h * 64 + dt * 16 + l15] = (__bf16)(o[1][dt][r] * inv1);
    }
  }
}

// ---------------- launch ----------------
extern "C" void kernel_launch(void* const* d_in, const int* in_sizes, int n_in,
                              void* d_out, int out_size, void* d_ws, size_t ws_size,
                              hipStream_t stream) {
  const float* x = (const float*)d_in[0];      // [8192,1024]
  const float* w_qkv = (const float*)d_in[1];  // [1024,3072]
  const float* w_out = (const float*)d_in[2];  // [1024,1024]
  const float* b_out = (const float*)d_in[3];  // [1024]
  float* out = (float*)d_out;

  char* ws = (char*)d_ws;
  __bf16* xb    = (__bf16*)(ws);                 // 16 MiB
  __bf16* wqkvt = (__bf16*)(ws + 16777216);      // 6 MiB
  __bf16* woutt = (__bf16*)(ws + 23068672);      // 2 MiB
  __bf16* qw    = (__bf16*)(ws + 25165824);
  __bf16* kw    = (__bf16*)(ws + 41943040);
  __bf16* vw    = (__bf16*)(ws + 58720256);      // end = 75497472
  __bf16* ao    = xb;  // alias: xb dead after QKV GEMM

  cast_x_kernel<<<8192, 256, 0, stream>>>(x, xb);
  transpose_cast_kernel<<<dim3(96, 32), dim3(32, 8), 0, stream>>>(w_qkv, wqkvt, 1024, 3072);
  transpose_cast_kernel<<<dim3(32, 32), dim3(32, 8), 0, stream>>>(w_out, woutt, 1024, 1024);
  gemm_bt_kernel<<<dim3(24, 64), 256, 0, stream>>>(xb, wqkvt, 0, qw, kw, vw, nullptr, nullptr);
  attn_kernel<<<1024, 256, 0, stream>>>(qw, kw, vw, ao);
  gemm_bt_kernel<<<dim3(8, 64), 256, 0, stream>>>(ao, woutt, 1, nullptr, nullptr, nullptr, out, b_out);
}

// Round 4
// 318.089 us; speedup vs baseline: 1.2135x; 1.0435x over previous
//
#include <hip/hip_runtime.h>

typedef __bf16 bf16x8 __attribute__((ext_vector_type(8)));
typedef __bf16 bf16x4 __attribute__((ext_vector_type(4)));
typedef float  f32x4  __attribute__((ext_vector_type(4)));

#define MFMA16(a, b, c) __builtin_amdgcn_mfma_f32_16x16x32_bf16(a, b, c, 0, 0, 0)
// async global->LDS, 16B per lane; LDS dest = wave-uniform base + lane*16
#define GLL(gp, lp) __builtin_amdgcn_global_load_lds( \
    (__attribute__((address_space(1))) void*)(gp),    \
    (__attribute__((address_space(3))) void*)(lp), 16, 0, 0)

// ---------------- cast fp32 -> bf16 (vectorized) ----------------
__global__ __launch_bounds__(256) void cast_x_kernel(const float* __restrict__ in,
                                                     __bf16* __restrict__ out) {
  int i = blockIdx.x * 256 + threadIdx.x;
  const float4 v = ((const float4*)in)[i];
  bf16x4 o = {(__bf16)v.x, (__bf16)v.y, (__bf16)v.z, (__bf16)v.w};
  ((bf16x4*)out)[i] = o;
}

// ---------------- transpose + cast: out[n][k] = (bf16)in[k][n] ----------------
__global__ void transpose_cast_kernel(const float* __restrict__ in,
                                      __bf16* __restrict__ out,
                                      int rows, int cols) {
  __shared__ float tile[32][33];
  int tx = threadIdx.x, ty = threadIdx.y;
  int x = blockIdx.x * 32 + tx;
  int y0 = blockIdx.y * 32;
#pragma unroll
  for (int i = 0; i < 32; i += 8)
    tile[ty + i][tx] = in[(y0 + ty + i) * cols + x];
  __syncthreads();
  int ox = y0 + tx;
  int oy0 = blockIdx.x * 32;
#pragma unroll
  for (int i = 0; i < 32; i += 8)
    out[(oy0 + ty + i) * rows + ox] = (__bf16)tile[tx][ty + i];
}

// ---------------- GEMM: C[M,N] = A[M,1024] * Bt[N,1024]^T ----------------
// 128x128 tile, BK=32, DOUBLE-BUFFERED global_load_lds prefetch:
// issue tile k+1 into buf^1, compute tile k from buf, single barrier/iter.
// The barrier's vmcnt(0) drain lands AFTER 16 MFMAs instead of before them.
#define QSCALE 0.045084220027780106f
__global__ __launch_bounds__(256) void gemm_bt_kernel(
    const __bf16* __restrict__ A, const __bf16* __restrict__ Bt, int mode,
    __bf16* __restrict__ qo, __bf16* __restrict__ ko, __bf16* __restrict__ vo,
    float* __restrict__ outp, const float* __restrict__ bias) {
  __shared__ __bf16 As[2][128 * 32];
  __shared__ __bf16 Bs[2][128 * 32];
  const int tid = threadIdx.x;
  const int m0 = blockIdx.y * 128, n0 = blockIdx.x * 128;
  const int w = tid >> 6, lane = tid & 63;
  const int quad = lane >> 4, l15 = lane & 15;
  const int wm = (w >> 1) * 64, wn = (w & 1) * 64;
  f32x4 acc[4][4] = {};
  const int sr = tid >> 2;
  const int sc = (tid & 3) * 8;
  const __bf16* ag = A + (m0 + sr) * 1024 + sc;
  const __bf16* bg = Bt + (n0 + sr) * 1024 + sc;

  auto stage = [&](int kk, __bf16* Ad, __bf16* Bd) {
    GLL(ag + kk, Ad + w * 512);
    GLL(ag + 64 * 1024 + kk, Ad + 2048 + w * 512);
    GLL(bg + kk, Bd + w * 512);
    GLL(bg + 64 * 1024 + kk, Bd + 2048 + w * 512);
  };
  auto compute = [&](const __bf16* Asb, const __bf16* Bsb) {
    bf16x8 af[4], bfr[4];
#pragma unroll
    for (int i = 0; i < 4; ++i)
      af[i] = *(const bf16x8*)(Asb + (wm + i * 16 + l15) * 32 + quad * 8);
#pragma unroll
    for (int j = 0; j < 4; ++j)
      bfr[j] = *(const bf16x8*)(Bsb + (wn + j * 16 + l15) * 32 + quad * 8);
#pragma unroll
    for (int i = 0; i < 4; ++i)
#pragma unroll
      for (int j = 0; j < 4; ++j)
        acc[i][j] = MFMA16(af[i], bfr[j], acc[i][j]);
  };

  stage(0, As[0], Bs[0]);
  __syncthreads();  // buf0 ready
  for (int k0 = 0; k0 < 1024; k0 += 64) {
    stage(k0 + 32, As[1], Bs[1]);   // prefetch odd tile
    compute(As[0], Bs[0]);          // compute even tile (hides prefetch)
    __syncthreads();                // odd tile ready; everyone done with buf0
    if (k0 + 64 < 1024) stage(k0 + 64, As[0], Bs[0]);
    compute(As[1], Bs[1]);
    __syncthreads();
  }

  if (mode == 0) {
#pragma unroll
    for (int i = 0; i < 4; ++i) {
#pragma unroll
      for (int j = 0; j < 4; ++j) {
        int gc = n0 + wn + j * 16 + l15;
        int which = gc >> 10, rem = gc & 1023;
        int h = rem >> 6, dd = rem & 63;
#pragma unroll
        for (int r = 0; r < 4; ++r) {
          int gm = m0 + wm + i * 16 + quad * 4 + r;
          int b = gm >> 10, n = gm & 1023;
          int bh = b * 16 + h;
          float v = acc[i][j][r];
          if (which == 0)       qo[(bh * 1024 + n) * 64 + dd] = (__bf16)(v * QSCALE);
          else if (which == 1)  ko[(bh * 1024 + n) * 64 + dd] = (__bf16)v;
          else                  vo[(bh * 64 + dd) * 1024 + n] = (__bf16)v;
        }
      }
    }
  } else {
#pragma unroll
    for (int j = 0; j < 4; ++j) {
      int gc = n0 + wn + j * 16 + l15;
      float bv = bias[gc];
#pragma unroll
      for (int i = 0; i < 4; ++i)
#pragma unroll
        for (int r = 0; r < 4; ++r) {
          int gm = m0 + wm + i * 16 + quad * 4 + r;
          outp[gm * 1024 + gc] = acc[i][j][r] + bv;
        }
    }
  }
}

// ---------------- attention, S^T formulation, no-max exp2 softmax ----------------
// grid: 1024 blocks (bh = blk>>3, qtile = blk&7), 4 waves, 32 Q rows/wave.
// q prescaled by SCALE*log2e. k: [bh][n][64], vt: [bh][64][n].
// LDS exactly 40960 B -> 4 blocks/CU. All buffers XOR-swizzled, unpadded.
__global__ __launch_bounds__(256, 4) void attn_kernel(
    const __bf16* __restrict__ q, const __bf16* __restrict__ k,
    const __bf16* __restrict__ vt, __bf16* __restrict__ ao) {
  __shared__ __bf16 Ks[128 * 64];    // [j][d], col granule g -> g ^ (j&7)
  __shared__ __bf16 Vs[64 * 128];    // [d][j], col granule g -> g ^ (d&15)
  __shared__ __bf16 Ps[4][32 * 32];  // per-wave P quarter [i32][j32], g -> g ^ (i&3)
  const int tid = threadIdx.x;
  const int bh = blockIdx.x >> 3, qt = blockIdx.x & 7;
  const int w = tid >> 6, lane = tid & 63;
  const int quad = lane >> 4, l15 = lane & 15;
  const int qrow = qt * 128 + w * 32;
  const __bf16* qb = q + (bh * 1024 + qrow) * 64;
  bf16x8 qf[2][2];
#pragma unroll
  for (int f = 0; f < 2; ++f) {
    qf[f][0] = *(const bf16x8*)(qb + (f * 16 + l15) * 64 + quad * 8);
    qf[f][1] = *(const bf16x8*)(qb + (f * 16 + l15) * 64 + 32 + quad * 8);
  }
  f32x4 o[2][4] = {};
  float rs0 = 0.f, rs1 = 0.f;
  const int krow = tid >> 3, kg8 = tid & 7;
  const __bf16* kg = k + (bh * 1024 + krow) * 64 + kg8 * 8;
  const int ksw = ((kg8 ^ (krow & 7)) * 8);
  const int vrow = tid >> 2, vg4 = tid & 3;
  const __bf16* vg = vt + (bh * 64 + vrow) * 1024 + vg4 * 8;
  const int kfs0 = (quad ^ (l15 & 7)) * 8;
  const int kfs1 = ((4 + quad) ^ (l15 & 7)) * 8;
  __bf16* pw = Ps[w];
  const int psw = quad ^ (l15 & 3);
  for (int j0 = 0; j0 < 1024; j0 += 128) {
    bf16x8 kv[4], vv[4];
#pragma unroll
    for (int p = 0; p < 4; ++p) kv[p] = *(const bf16x8*)(kg + (j0 + p * 32) * 64);
#pragma unroll
    for (int p = 0; p < 4; ++p) vv[p] = *(const bf16x8*)(vg + j0 + p * 32);
    __syncthreads();
#pragma unroll
    for (int p = 0; p < 4; ++p)
      *(bf16x8*)(Ks + (krow + p * 32) * 64 + ksw) = kv[p];
#pragma unroll
    for (int p = 0; p < 4; ++p)
      *(bf16x8*)(Vs + vrow * 128 + (((p * 4 + vg4) ^ (vrow & 15)) * 8)) = vv[p];
    __syncthreads();
    bf16x4 pk[2][8];
#pragma unroll
    for (int t = 0; t < 8; ++t) {
      const __bf16* kr = Ks + (t * 16 + l15) * 64;
      bf16x8 kf0 = *(const bf16x8*)(kr + kfs0);
      bf16x8 kf1 = *(const bf16x8*)(kr + kfs1);
      f32x4 z0 = {}, z1 = {};
      z0 = MFMA16(kf0, qf[0][0], z0);
      z0 = MFMA16(kf1, qf[0][1], z0);
      z1 = MFMA16(kf0, qf[1][0], z1);
      z1 = MFMA16(kf1, qf[1][1], z1);
      float p00 = exp2f(z0[0]), p01 = exp2f(z0[1]), p02 = exp2f(z0[2]), p03 = exp2f(z0[3]);
      float p10 = exp2f(z1[0]), p11 = exp2f(z1[1]), p12 = exp2f(z1[2]), p13 = exp2f(z1[3]);
      rs0 += (p00 + p01) + (p02 + p03);
      rs1 += (p10 + p11) + (p12 + p13);
      pk[0][t] = (bf16x4){(__bf16)p00, (__bf16)p01, (__bf16)p02, (__bf16)p03};
      pk[1][t] = (bf16x4){(__bf16)p10, (__bf16)p11, (__bf16)p12, (__bf16)p13};
    }
#pragma unroll
    for (int Q = 0; Q < 4; ++Q) {
#pragma unroll
      for (int f = 0; f < 2; ++f)
#pragma unroll
        for (int tl = 0; tl < 2; ++tl) {
          int g = (2 * tl + (quad >> 1)) ^ (l15 & 3);
          *(bf16x4*)(pw + (f * 16 + l15) * 32 + g * 8 + (quad & 1) * 4) = pk[f][2 * Q + tl];
        }
      bf16x8 pf0 = *(const bf16x8*)(pw + l15 * 32 + psw * 8);
      bf16x8 pf1 = *(const bf16x8*)(pw + (16 + l15) * 32 + psw * 8);
#pragma unroll
      for (int dt = 0; dt < 4; ++dt) {
        bf16x8 vf = *(const bf16x8*)(Vs + (dt * 16 + l15) * 128 + (((Q * 4 + quad) ^ l15) * 8));
        o[0][dt] = MFMA16(pf0, vf, o[0][dt]);
        o[1][dt] = MFMA16(pf1, vf, o[1][dt]);
      }
    }
  }
  rs0 += __shfl_xor(rs0, 16); rs0 += __shfl_xor(rs0, 32);
  rs1 += __shfl_xor(rs1, 16); rs1 += __shfl_xor(rs1, 32);
  const int b = bh >> 4, h = bh & 15;
  const int qbase = quad << 4;
#pragma unroll
  for (int r = 0; r < 4; ++r) {
    int src = qbase | (quad * 4 + r);
    float inv0 = 1.0f / __shfl(rs0, src);
    float inv1 = 1.0f / __shfl(rs1, src);
    long row0 = b * 1024 + qrow + quad * 4 + r;
    long row1 = row0 + 16;
#pragma unroll
    for (int dt = 0; dt < 4; ++dt) {
      ao[row0 * 1024 + h * 64 + dt * 16 + l15] = (__bf16)(o[0][dt][r] * inv0);
      ao[row1 * 1024 + h * 64 + dt * 16 + l15] = (__bf16)(o[1][dt][r] * inv1);
    }
  }
}

// ---------------- launch ----------------
extern "C" void kernel_launch(void* const* d_in, const int* in_sizes, int n_in,
                              void* d_out, int out_size, void* d_ws, size_t ws_size,
                              hipStream_t stream) {
  const float* x = (const float*)d_in[0];      // [8192,1024]
  const float* w_qkv = (const float*)d_in[1];  // [1024,3072]
  const float* w_out = (const float*)d_in[2];  // [1024,1024]
  const float* b_out = (const float*)d_in[3];  // [1024]
  float* out = (float*)d_out;

  char* ws = (char*)d_ws;
  __bf16* xb    = (__bf16*)(ws);                 // 16 MiB
  __bf16* wqkvt = (__bf16*)(ws + 16777216);      // 6 MiB
  __bf16* woutt = (__bf16*)(ws + 23068672);      // 2 MiB
  __bf16* qw    = (__bf16*)(ws + 25165824);
  __bf16* kw    = (__bf16*)(ws + 41943040);
  __bf16* vw    = (__bf16*)(ws + 58720256);      // end = 75497472
  __bf16* ao    = xb;  // alias: xb dead after QKV GEMM

  cast_x_kernel<<<8192, 256, 0, stream>>>(x, xb);
  transpose_cast_kernel<<<dim3(96, 32), dim3(32, 8), 0, stream>>>(w_qkv, wqkvt, 1024, 3072);
  transpose_cast_kernel<<<dim3(32, 32), dim3(32, 8), 0, stream>>>(w_out, woutt, 1024, 1024);
  gemm_bt_kernel<<<dim3(24, 64), 256, 0, stream>>>(xb, wqkvt, 0, qw, kw, vw, nullptr, nullptr);
  attn_kernel<<<1024, 256, 0, stream>>>(qw, kw, vw, ao);
  gemm_bt_kernel<<<dim3(8, 64), 256, 0, stream>>>(ao, woutt, 1, nullptr, nullptr, nullptr, out, b_out);
}

// Round 6
// 289.080 us; speedup vs baseline: 1.3353x; 1.1003x over previous
//
#include <hip/hip_runtime.h>

typedef __bf16 bf16x8 __attribute__((ext_vector_type(8)));
typedef __bf16 bf16x4 __attribute__((ext_vector_type(4)));
typedef float  f32x4  __attribute__((ext_vector_type(4)));

#define MFMA16(a, b, c) __builtin_amdgcn_mfma_f32_16x16x32_bf16(a, b, c, 0, 0, 0)
// async global->LDS, 16B per lane; LDS dest = wave-uniform base + lane*16
#define GLL(gp, lp) __builtin_amdgcn_global_load_lds( \
    (__attribute__((address_space(1))) void*)(gp),    \
    (__attribute__((address_space(3))) void*)(lp), 16, 0, 0)
// Barrier with manual vmcnt (keeps N GLLs in flight across the barrier) AND
// lgkmcnt(0): each wave's queued ds_reads must PROCESS before the barrier
// releases buffer overwrite (round 5 omitted lgkmcnt -> WAR race in LDS).
#define WAITBAR(N) asm volatile("s_waitcnt vmcnt(" #N ") lgkmcnt(0)\n\ts_barrier" ::: "memory")

// ---------------- cast fp32 -> bf16 (vectorized) ----------------
__global__ __launch_bounds__(256) void cast_x_kernel(const float* __restrict__ in,
                                                     __bf16* __restrict__ out) {
  int i = blockIdx.x * 256 + threadIdx.x;
  const float4 v = ((const float4*)in)[i];
  bf16x4 o = {(__bf16)v.x, (__bf16)v.y, (__bf16)v.z, (__bf16)v.w};
  ((bf16x4*)out)[i] = o;
}

// ---------------- transpose + cast: out[n][k] = (bf16)in[k][n] ----------------
__global__ void transpose_cast_kernel(const float* __restrict__ in,
                                      __bf16* __restrict__ out,
                                      int rows, int cols) {
  __shared__ float tile[32][33];
  int tx = threadIdx.x, ty = threadIdx.y;
  int x = blockIdx.x * 32 + tx;
  int y0 = blockIdx.y * 32;
#pragma unroll
  for (int i = 0; i < 32; i += 8)
    tile[ty + i][tx] = in[(y0 + ty + i) * cols + x];
  __syncthreads();
  int ox = y0 + tx;
  int oy0 = blockIdx.x * 32;
#pragma unroll
  for (int i = 0; i < 32; i += 8)
    out[(oy0 + ty + i) * rows + ox] = (__bf16)tile[tx][ty + i];
}

// ---------------- GEMM: C[M,N] = A[M,1024] * Bt[N,1024]^T ----------------
// 128x128 tile, BK=32, 3-buffer depth-2 pipeline: tile t+2 prefetched while
// computing tile t; WAITBAR(4) keeps 4 GLLs in flight across each barrier.
#define QSCALE 0.045084220027780106f
__global__ __launch_bounds__(256) void gemm_bt_kernel(
    const __bf16* __restrict__ A, const __bf16* __restrict__ Bt, int mode,
    __bf16* __restrict__ qo, __bf16* __restrict__ ko, __bf16* __restrict__ vo,
    float* __restrict__ outp, const float* __restrict__ bias) {
  __shared__ __bf16 LDS[3][2][4096];  // [buf][A/B][128*32] = 48 KiB
  const int tid = threadIdx.x;
  const int m0 = blockIdx.y * 128, n0 = blockIdx.x * 128;
  const int w = tid >> 6, lane = tid & 63;
  const int quad = lane >> 4, l15 = lane & 15;
  const int wm = (w >> 1) * 64, wn = (w & 1) * 64;
  f32x4 acc[4][4] = {};
  const int sr = tid >> 2;
  const int sc = (tid & 3) * 8;
  const __bf16* ag = A + (m0 + sr) * 1024 + sc;
  const __bf16* bg = Bt + (n0 + sr) * 1024 + sc;

  auto stage = [&](int T, int b) {
    const int kk = T * 32;
    GLL(ag + kk,             &LDS[b][0][0] + w * 512);
    GLL(ag + 64 * 1024 + kk, &LDS[b][0][0] + 2048 + w * 512);
    GLL(bg + kk,             &LDS[b][1][0] + w * 512);
    GLL(bg + 64 * 1024 + kk, &LDS[b][1][0] + 2048 + w * 512);
  };
  auto compute = [&](int b) {
    const __bf16* Asb = &LDS[b][0][0];
    const __bf16* Bsb = &LDS[b][1][0];
    bf16x8 af[4], bfr[4];
#pragma unroll
    for (int i = 0; i < 4; ++i)
      af[i] = *(const bf16x8*)(Asb + (wm + i * 16 + l15) * 32 + quad * 8);
#pragma unroll
    for (int j = 0; j < 4; ++j)
      bfr[j] = *(const bf16x8*)(Bsb + (wn + j * 16 + l15) * 32 + quad * 8);
#pragma unroll
    for (int i = 0; i < 4; ++i)
#pragma unroll
      for (int j = 0; j < 4; ++j)
        acc[i][j] = MFMA16(af[i], bfr[j], acc[i][j]);
  };

  // pipeline: tiles 0..31, tile t lives in buf t%3
  stage(0, 0);
  stage(1, 1);
  WAITBAR(4);                    // tile 0 ready (tile 1 still in flight)
  for (int g = 0; g < 10; ++g) {
    const int t = g * 3;
    stage(t + 2, 2); compute(0); WAITBAR(4);
    stage(t + 3, 0); compute(1); WAITBAR(4);
    stage(t + 4, 1); compute(2); WAITBAR(4);
  }
  compute(0);                    // tile 30
  asm volatile("s_waitcnt vmcnt(0) lgkmcnt(0)\n\ts_barrier" ::: "memory");
  compute(1);                    // tile 31
  __syncthreads();               // LDS free for epilogue scratch

  // ---- epilogue ----
  const int gcw = n0 + wn;       // wave's 64-col base (one tensor, one head)
  float* T = (float*)(&LDS[0][0][0]) + w * 1088;  // per-wave [16][68] f32
  if (mode == 0) {
    const int which = gcw >> 10;
    const int h = (gcw & 1023) >> 6;
    if (which == 2) {
      // V: acc rows = consecutive tokens => packed bf16x4 stores into vt[.][d][n]
#pragma unroll
      for (int i = 0; i < 4; ++i) {
        int gm = m0 + wm + i * 16 + quad * 4;
        int b = gm >> 10, n = gm & 1023;
        __bf16* vb = vo + ((long)(b * 16 + h) * 64) * 1024 + n;
#pragma unroll
        for (int j = 0; j < 4; ++j) {
          int dd = j * 16 + l15;
          bf16x4 pv = {(__bf16)acc[i][j][0], (__bf16)acc[i][j][1],
                       (__bf16)acc[i][j][2], (__bf16)acc[i][j][3]};
          *(bf16x4*)(vb + (long)dd * 1024) = pv;
        }
      }
    } else {
      // Q/K: LDS transpose -> 16B coalesced stores
      __bf16* dst = (which == 0) ? qo : ko;
      const float scl = (which == 0) ? QSCALE : 1.0f;
#pragma unroll
      for (int i = 0; i < 4; ++i) {
#pragma unroll
        for (int j = 0; j < 4; ++j)
#pragma unroll
          for (int r = 0; r < 4; ++r)
            T[(quad * 4 + r) * 68 + j * 16 + l15] = acc[i][j][r];
        // wave-synchronous LDS round-trip (same-wave DS ordering)
        const float* Tr = T + l15 * 68 + quad * 16;
        f32x4 c0 = *(const f32x4*)(Tr);
        f32x4 c1 = *(const f32x4*)(Tr + 4);
        f32x4 c2 = *(const f32x4*)(Tr + 8);
        f32x4 c3 = *(const f32x4*)(Tr + 12);
        int gm = m0 + wm + i * 16 + l15;
        int b = gm >> 10, n = gm & 1023;
        __bf16* p = dst + ((long)((b * 16 + h) * 1024 + n)) * 64 + quad * 16;
        bf16x8 o0 = {(__bf16)(c0[0] * scl), (__bf16)(c0[1] * scl),
                     (__bf16)(c0[2] * scl), (__bf16)(c0[3] * scl),
                     (__bf16)(c1[0] * scl), (__bf16)(c1[1] * scl),
                     (__bf16)(c1[2] * scl), (__bf16)(c1[3] * scl)};
        bf16x8 o1 = {(__bf16)(c2[0] * scl), (__bf16)(c2[1] * scl),
                     (__bf16)(c2[2] * scl), (__bf16)(c2[3] * scl),
                     (__bf16)(c3[0] * scl), (__bf16)(c3[1] * scl),
                     (__bf16)(c3[2] * scl), (__bf16)(c3[3] * scl)};
        *(bf16x8*)p = o0;
        *(bf16x8*)(p + 8) = o1;
      }
    }
  } else {
    // out-proj: LDS transpose -> f32x4 stores + bias
    const int cb = gcw;
    f32x4 bv[4];
#pragma unroll
    for (int c = 0; c < 4; ++c)
      bv[c] = *(const f32x4*)(bias + cb + quad * 16 + c * 4);
#pragma unroll
    for (int i = 0; i < 4; ++i) {
#pragma unroll
      for (int j = 0; j < 4; ++j)
#pragma unroll
        for (int r = 0; r < 4; ++r)
          T[(quad * 4 + r) * 68 + j * 16 + l15] = acc[i][j][r];
      const float* Tr = T + l15 * 68 + quad * 16;
      int gm = m0 + wm + i * 16 + l15;
      float* p = outp + (long)gm * 1024 + cb + quad * 16;
#pragma unroll
      for (int c = 0; c < 4; ++c) {
        f32x4 v = *(const f32x4*)(Tr + c * 4);
        v += bv[c];
        *(f32x4*)(p + c * 4) = v;
      }
    }
  }
}

// ---------------- attention, S^T formulation, no-max exp2 softmax ----------------
// grid: 1024 blocks (bh = blk>>3, qtile = blk&7), 4 waves, 32 Q rows/wave.
// q prescaled by SCALE*log2e. k: [bh][n][64], vt: [bh][64][n].
__global__ __launch_bounds__(256, 4) void attn_kernel(
    const __bf16* __restrict__ q, const __bf16* __restrict__ k,
    const __bf16* __restrict__ vt, __bf16* __restrict__ ao) {
  __shared__ __bf16 Ks[128 * 64];    // [j][d], col granule g -> g ^ (j&7)
  __shared__ __bf16 Vs[64 * 128];    // [d][j], col granule g -> g ^ (d&15)
  __shared__ __bf16 Ps[4][32 * 32];  // per-wave P quarter [i32][j32]
  const int tid = threadIdx.x;
  const int bh = blockIdx.x >> 3, qt = blockIdx.x & 7;
  const int w = tid >> 6, lane = tid & 63;
  const int quad = lane >> 4, l15 = lane & 15;
  const int qrow = qt * 128 + w * 32;
  const __bf16* qb = q + (bh * 1024 + qrow) * 64;
  bf16x8 qf[2][2];
#pragma unroll
  for (int f = 0; f < 2; ++f) {
    qf[f][0] = *(const bf16x8*)(qb + (f * 16 + l15) * 64 + quad * 8);
    qf[f][1] = *(const bf16x8*)(qb + (f * 16 + l15) * 64 + 32 + quad * 8);
  }
  f32x4 o[2][4] = {};
  float rs0 = 0.f, rs1 = 0.f;
  const int krow = tid >> 3, kg8 = tid & 7;
  const __bf16* kg = k + (bh * 1024 + krow) * 64 + kg8 * 8;
  const int ksw = ((kg8 ^ (krow & 7)) * 8);
  const int vrow = tid >> 2, vg4 = tid & 3;
  const __bf16* vg = vt + (bh * 64 + vrow) * 1024 + vg4 * 8;
  const int kfs0 = (quad ^ (l15 & 7)) * 8;
  const int kfs1 = ((4 + quad) ^ (l15 & 7)) * 8;
  __bf16* pw = Ps[w];
  const int psw = quad ^ (l15 & 3);
  for (int j0 = 0; j0 < 1024; j0 += 128) {
    bf16x8 kv[4], vv[4];
#pragma unroll
    for (int p = 0; p < 4; ++p) kv[p] = *(const bf16x8*)(kg + (j0 + p * 32) * 64);
#pragma unroll
    for (int p = 0; p < 4; ++p) vv[p] = *(const bf16x8*)(vg + j0 + p * 32);
    __syncthreads();
#pragma unroll
    for (int p = 0; p < 4; ++p)
      *(bf16x8*)(Ks + (krow + p * 32) * 64 + ksw) = kv[p];
#pragma unroll
    for (int p = 0; p < 4; ++p)
      *(bf16x8*)(Vs + vrow * 128 + (((p * 4 + vg4) ^ (vrow & 15)) * 8)) = vv[p];
    __syncthreads();
    bf16x4 pk[2][8];
#pragma unroll
    for (int t = 0; t < 8; ++t) {
      const __bf16* kr = Ks + (t * 16 + l15) * 64;
      bf16x8 kf0 = *(const bf16x8*)(kr + kfs0);
      bf16x8 kf1 = *(const bf16x8*)(kr + kfs1);
      f32x4 z0 = {}, z1 = {};
      z0 = MFMA16(kf0, qf[0][0], z0);
      z0 = MFMA16(kf1, qf[0][1], z0);
      z1 = MFMA16(kf0, qf[1][0], z1);
      z1 = MFMA16(kf1, qf[1][1], z1);
      float p00 = exp2f(z0[0]), p01 = exp2f(z0[1]), p02 = exp2f(z0[2]), p03 = exp2f(z0[3]);
      float p10 = exp2f(z1[0]), p11 = exp2f(z1[1]), p12 = exp2f(z1[2]), p13 = exp2f(z1[3]);
      rs0 += (p00 + p01) + (p02 + p03);
      rs1 += (p10 + p11) + (p12 + p13);
      pk[0][t] = (bf16x4){(__bf16)p00, (__bf16)p01, (__bf16)p02, (__bf16)p03};
      pk[1][t] = (bf16x4){(__bf16)p10, (__bf16)p11, (__bf16)p12, (__bf16)p13};
    }
#pragma unroll
    for (int Q = 0; Q < 4; ++Q) {
#pragma unroll
      for (int f = 0; f < 2; ++f)
#pragma unroll
        for (int tl = 0; tl < 2; ++tl) {
          int g = (2 * tl + (quad >> 1)) ^ (l15 & 3);
          *(bf16x4*)(pw + (f * 16 + l15) * 32 + g * 8 + (quad & 1) * 4) = pk[f][2 * Q + tl];
        }
      bf16x8 pf0 = *(const bf16x8*)(pw + l15 * 32 + psw * 8);
      bf16x8 pf1 = *(const bf16x8*)(pw + (16 + l15) * 32 + psw * 8);
#pragma unroll
      for (int dt = 0; dt < 4; ++dt) {
        bf16x8 vf = *(const bf16x8*)(Vs + (dt * 16 + l15) * 128 + (((Q * 4 + quad) ^ l15) * 8));
        o[0][dt] = MFMA16(pf0, vf, o[0][dt]);
        o[1][dt] = MFMA16(pf1, vf, o[1][dt]);
      }
    }
  }
  rs0 += __shfl_xor(rs0, 16); rs0 += __shfl_xor(rs0, 32);
  rs1 += __shfl_xor(rs1, 16); rs1 += __shfl_xor(rs1, 32);
  const int b = bh >> 4, h = bh & 15;
  const int qbase = quad << 4;
#pragma unroll
  for (int r = 0; r < 4; ++r) {
    int src = qbase | (quad * 4 + r);
    float inv0 = 1.0f / __shfl(rs0, src);
    float inv1 = 1.0f / __shfl(rs1, src);
    long row0 = b * 1024 + qrow + quad * 4 + r;
    long row1 = row0 + 16;
#pragma unroll
    for (int dt = 0; dt < 4; ++dt) {
      ao[row0 * 1024 + h * 64 + dt * 16 + l15] = (__bf16)(o[0][dt][r] * inv0);
      ao[row1 * 1024 + h * 64 + dt * 16 + l15] = (__bf16)(o[1][dt][r] * inv1);
    }
  }
}

// ---------------- launch ----------------
extern "C" void kernel_launch(void* const* d_in, const int* in_sizes, int n_in,
                              void* d_out, int out_size, void* d_ws, size_t ws_size,
                              hipStream_t stream) {
  const float* x = (const float*)d_in[0];      // [8192,1024]
  const float* w_qkv = (const float*)d_in[1];  // [1024,3072]
  const float* w_out = (const float*)d_in[2];  // [1024,1024]
  const float* b_out = (const float*)d_in[3];  // [1024]
  float* out = (float*)d_out;

  char* ws = (char*)d_ws;
  __bf16* xb    = (__bf16*)(ws);                 // 16 MiB
  __bf16* wqkvt = (__bf16*)(ws + 16777216);      // 6 MiB
  __bf16* woutt = (__bf16*)(ws + 23068672);      // 2 MiB
  __bf16* qw    = (__bf16*)(ws + 25165824);
  __bf16* kw    = (__bf16*)(ws + 41943040);
  __bf16* vw    = (__bf16*)(ws + 58720256);      // end = 75497472
  __bf16* ao    = xb;  // alias: xb dead after QKV GEMM

  cast_x_kernel<<<8192, 256, 0, stream>>>(x, xb);
  transpose_cast_kernel<<<dim3(96, 32), dim3(32, 8), 0, stream>>>(w_qkv, wqkvt, 1024, 3072);
  transpose_cast_kernel<<<dim3(32, 32), dim3(32, 8), 0, stream>>>(w_out, woutt, 1024, 1024);
  gemm_bt_kernel<<<dim3(24, 64), 256, 0, stream>>>(xb, wqkvt, 0, qw, kw, vw, nullptr, nullptr);
  attn_kernel<<<1024, 256, 0, stream>>>(qw, kw, vw, ao);
  gemm_bt_kernel<<<dim3(8, 64), 256, 0, stream>>>(ao, woutt, 1, nullptr, nullptr, nullptr, out, b_out);
}

// Round 7
// 275.988 us; speedup vs baseline: 1.3986x; 1.0474x over previous
//
#include <hip/hip_runtime.h>

typedef __bf16 bf16x8 __attribute__((ext_vector_type(8)));
typedef __bf16 bf16x4 __attribute__((ext_vector_type(4)));
typedef float  f32x4  __attribute__((ext_vector_type(4)));

#define MFMA16(a, b, c) __builtin_amdgcn_mfma_f32_16x16x32_bf16(a, b, c, 0, 0, 0)
// async global->LDS, 16B per lane; LDS dest = wave-uniform base + lane*16
#define GLL(gp, lp) __builtin_amdgcn_global_load_lds( \
    (__attribute__((address_space(1))) void*)(gp),    \
    (__attribute__((address_space(3))) void*)(lp), 16, 0, 0)
// Barrier with manual vmcnt (keeps N GLLs in flight across the barrier) AND
// lgkmcnt(0) so queued ds_reads complete before buffers are overwritten.
#define WAITBAR(N) asm volatile("s_waitcnt vmcnt(" #N ") lgkmcnt(0)\n\ts_barrier" ::: "memory")

// ---------------- cast fp32 -> bf16 (vectorized) ----------------
__global__ __launch_bounds__(256) void cast_x_kernel(const float* __restrict__ in,
                                                     __bf16* __restrict__ out) {
  int i = blockIdx.x * 256 + threadIdx.x;
  const float4 v = ((const float4*)in)[i];
  bf16x4 o = {(__bf16)v.x, (__bf16)v.y, (__bf16)v.z, (__bf16)v.w};
  ((bf16x4*)out)[i] = o;
}

// ---------------- transpose + cast: out[n][k] = (bf16)in[k][n] ----------------
__global__ void transpose_cast_kernel(const float* __restrict__ in,
                                      __bf16* __restrict__ out,
                                      int rows, int cols) {
  __shared__ float tile[32][33];
  int tx = threadIdx.x, ty = threadIdx.y;
  int x = blockIdx.x * 32 + tx;
  int y0 = blockIdx.y * 32;
#pragma unroll
  for (int i = 0; i < 32; i += 8)
    tile[ty + i][tx] = in[(y0 + ty + i) * cols + x];
  __syncthreads();
  int ox = y0 + tx;
  int oy0 = blockIdx.x * 32;
#pragma unroll
  for (int i = 0; i < 32; i += 8)
    out[(oy0 + ty + i) * rows + ox] = (__bf16)tile[tx][ty + i];
}

// ---------------- GEMM: C[M,N] = A[M,1024] * Bt[N,1024]^T ----------------
// 128x128 tile, BK=32, 3-buffer depth-2 pipeline, WAITBAR(4).
// Flat grid + XCD swizzle: each XCD owns nx/8 consecutive n-tiles so its
// B-slice stays L2-resident while A streams.
#define QSCALE 0.045084220027780106f
__global__ __launch_bounds__(256) void gemm_bt_kernel(
    const __bf16* __restrict__ A, const __bf16* __restrict__ Bt, int mode, int nxg,
    __bf16* __restrict__ qo, __bf16* __restrict__ ko, __bf16* __restrict__ vo,
    float* __restrict__ outp, const float* __restrict__ bias) {
  __shared__ __bf16 LDS[3][2][4096];  // [buf][A/B][128*32] = 48 KiB
  const int tid = threadIdx.x;
  const int id = blockIdx.x;
  const int xcd = id & 7, s = id >> 3;
  const int bx = xcd * nxg + (nxg == 3 ? s % 3 : 0);
  const int by = (nxg == 3 ? s / 3 : s);
  const int m0 = by * 128, n0 = bx * 128;
  const int w = tid >> 6, lane = tid & 63;
  const int quad = lane >> 4, l15 = lane & 15;
  const int wm = (w >> 1) * 64, wn = (w & 1) * 64;
  f32x4 acc[4][4] = {};
  const int sr = tid >> 2;
  const int sc = (tid & 3) * 8;
  const __bf16* ag = A + (m0 + sr) * 1024 + sc;
  const __bf16* bg = Bt + (n0 + sr) * 1024 + sc;

  auto stage = [&](int T, int b) {
    const int kk = T * 32;
    GLL(ag + kk,             &LDS[b][0][0] + w * 512);
    GLL(ag + 64 * 1024 + kk, &LDS[b][0][0] + 2048 + w * 512);
    GLL(bg + kk,             &LDS[b][1][0] + w * 512);
    GLL(bg + 64 * 1024 + kk, &LDS[b][1][0] + 2048 + w * 512);
  };
  auto compute = [&](int b) {
    const __bf16* Asb = &LDS[b][0][0];
    const __bf16* Bsb = &LDS[b][1][0];
    bf16x8 af[4], bfr[4];
#pragma unroll
    for (int i = 0; i < 4; ++i)
      af[i] = *(const bf16x8*)(Asb + (wm + i * 16 + l15) * 32 + quad * 8);
#pragma unroll
    for (int j = 0; j < 4; ++j)
      bfr[j] = *(const bf16x8*)(Bsb + (wn + j * 16 + l15) * 32 + quad * 8);
#pragma unroll
    for (int i = 0; i < 4; ++i)
#pragma unroll
      for (int j = 0; j < 4; ++j)
        acc[i][j] = MFMA16(af[i], bfr[j], acc[i][j]);
  };

  // pipeline: tiles 0..31, tile t lives in buf t%3
  stage(0, 0);
  stage(1, 1);
  WAITBAR(4);                    // tile 0 ready (tile 1 still in flight)
  for (int g = 0; g < 10; ++g) {
    const int t = g * 3;
    stage(t + 2, 2); compute(0); WAITBAR(4);
    stage(t + 3, 0); compute(1); WAITBAR(4);
    stage(t + 4, 1); compute(2); WAITBAR(4);
  }
  compute(0);                    // tile 30
  asm volatile("s_waitcnt vmcnt(0) lgkmcnt(0)\n\ts_barrier" ::: "memory");
  compute(1);                    // tile 31
  __syncthreads();               // LDS free for epilogue scratch

  // ---- epilogue ----
  const int gcw = n0 + wn;       // wave's 64-col base (one tensor, one head)
  float* T = (float*)(&LDS[0][0][0]) + w * 1088;  // per-wave [16][68] f32
  if (mode == 0) {
    const int which = gcw >> 10;
    const int h = (gcw & 1023) >> 6;
    if (which == 2) {
      // V: acc rows = consecutive tokens => packed bf16x4 stores into vt[.][d][n]
#pragma unroll
      for (int i = 0; i < 4; ++i) {
        int gm = m0 + wm + i * 16 + quad * 4;
        int b = gm >> 10, n = gm & 1023;
        __bf16* vb = vo + ((long)(b * 16 + h) * 64) * 1024 + n;
#pragma unroll
        for (int j = 0; j < 4; ++j) {
          int dd = j * 16 + l15;
          bf16x4 pv = {(__bf16)acc[i][j][0], (__bf16)acc[i][j][1],
                       (__bf16)acc[i][j][2], (__bf16)acc[i][j][3]};
          *(bf16x4*)(vb + (long)dd * 1024) = pv;
        }
      }
    } else {
      // Q/K: LDS transpose -> 16B coalesced stores
      __bf16* dst = (which == 0) ? qo : ko;
      const float scl = (which == 0) ? QSCALE : 1.0f;
#pragma unroll
      for (int i = 0; i < 4; ++i) {
#pragma unroll
        for (int j = 0; j < 4; ++j)
#pragma unroll
          for (int r = 0; r < 4; ++r)
            T[(quad * 4 + r) * 68 + j * 16 + l15] = acc[i][j][r];
        const float* Tr = T + l15 * 68 + quad * 16;
        f32x4 c0 = *(const f32x4*)(Tr);
        f32x4 c1 = *(const f32x4*)(Tr + 4);
        f32x4 c2 = *(const f32x4*)(Tr + 8);
        f32x4 c3 = *(const f32x4*)(Tr + 12);
        int gm = m0 + wm + i * 16 + l15;
        int b = gm >> 10, n = gm & 1023;
        __bf16* p = dst + ((long)((b * 16 + h) * 1024 + n)) * 64 + quad * 16;
        bf16x8 o0 = {(__bf16)(c0[0] * scl), (__bf16)(c0[1] * scl),
                     (__bf16)(c0[2] * scl), (__bf16)(c0[3] * scl),
                     (__bf16)(c1[0] * scl), (__bf16)(c1[1] * scl),
                     (__bf16)(c1[2] * scl), (__bf16)(c1[3] * scl)};
        bf16x8 o1 = {(__bf16)(c2[0] * scl), (__bf16)(c2[1] * scl),
                     (__bf16)(c2[2] * scl), (__bf16)(c2[3] * scl),
                     (__bf16)(c3[0] * scl), (__bf16)(c3[1] * scl),
                     (__bf16)(c3[2] * scl), (__bf16)(c3[3] * scl)};
        *(bf16x8*)p = o0;
        *(bf16x8*)(p + 8) = o1;
      }
    }
  } else {
    // out-proj: LDS transpose -> f32x4 stores + bias
    const int cb = gcw;
    f32x4 bv[4];
#pragma unroll
    for (int c = 0; c < 4; ++c)
      bv[c] = *(const f32x4*)(bias + cb + quad * 16 + c * 4);
#pragma unroll
    for (int i = 0; i < 4; ++i) {
#pragma unroll
      for (int j = 0; j < 4; ++j)
#pragma unroll
        for (int r = 0; r < 4; ++r)
          T[(quad * 4 + r) * 68 + j * 16 + l15] = acc[i][j][r];
      const float* Tr = T + l15 * 68 + quad * 16;
      int gm = m0 + wm + i * 16 + l15;
      float* p = outp + (long)gm * 1024 + cb + quad * 16;
#pragma unroll
      for (int c = 0; c < 4; ++c) {
        f32x4 v = *(const f32x4*)(Tr + c * 4);
        v += bv[c];
        *(f32x4*)(p + c * 4) = v;
      }
    }
  }
}

// ---------------- attention, S^T formulation, no-max exp2 softmax ----------------
// grid: 1024 blocks. XCD swizzle: bh = blk & 127, qt = blk >> 7, so all 8
// q-tile blocks of a bh satisfy blk % 8 == bh % 8 -> same XCD -> K/V stay in
// that XCD's L2 (16 bh x 262 KB ~ 4 MB) instead of being re-fetched 8x.
__global__ __launch_bounds__(256, 4) void attn_kernel(
    const __bf16* __restrict__ q, const __bf16* __restrict__ k,
    const __bf16* __restrict__ vt, __bf16* __restrict__ ao) {
  __shared__ __bf16 Ks[128 * 64];    // [j][d], col granule g -> g ^ (j&7)
  __shared__ __bf16 Vs[64 * 128];    // [d][j], col granule g -> g ^ (d&15)
  __shared__ __bf16 Ps[4][32 * 32];  // per-wave P quarter [i32][j32]
  const int tid = threadIdx.x;
  const int bh = blockIdx.x & 127, qt = blockIdx.x >> 7;
  const int w = tid >> 6, lane = tid & 63;
  const int quad = lane >> 4, l15 = lane & 15;
  const int qrow = qt * 128 + w * 32;
  const __bf16* qb = q + (bh * 1024 + qrow) * 64;
  bf16x8 qf[2][2];
#pragma unroll
  for (int f = 0; f < 2; ++f) {
    qf[f][0] = *(const bf16x8*)(qb + (f * 16 + l15) * 64 + quad * 8);
    qf[f][1] = *(const bf16x8*)(qb + (f * 16 + l15) * 64 + 32 + quad * 8);
  }
  f32x4 o[2][4] = {};
  float rs0 = 0.f, rs1 = 0.f;
  const int krow = tid >> 3, kg8 = tid & 7;
  const __bf16* kg = k + (bh * 1024 + krow) * 64 + kg8 * 8;
  const int ksw = ((kg8 ^ (krow & 7)) * 8);
  const int vrow = tid >> 2, vg4 = tid & 3;
  const __bf16* vg = vt + (bh * 64 + vrow) * 1024 + vg4 * 8;
  const int kfs0 = (quad ^ (l15 & 7)) * 8;
  const int kfs1 = ((4 + quad) ^ (l15 & 7)) * 8;
  __bf16* pw = Ps[w];
  const int psw = quad ^ (l15 & 3);
  for (int j0 = 0; j0 < 1024; j0 += 128) {
    bf16x8 kv[4], vv[4];
#pragma unroll
    for (int p = 0; p < 4; ++p) kv[p] = *(const bf16x8*)(kg + (j0 + p * 32) * 64);
#pragma unroll
    for (int p = 0; p < 4; ++p) vv[p] = *(const bf16x8*)(vg + j0 + p * 32);
    __syncthreads();
#pragma unroll
    for (int p = 0; p < 4; ++p)
      *(bf16x8*)(Ks + (krow + p * 32) * 64 + ksw) = kv[p];
#pragma unroll
    for (int p = 0; p < 4; ++p)
      *(bf16x8*)(Vs + vrow * 128 + (((p * 4 + vg4) ^ (vrow & 15)) * 8)) = vv[p];
    __syncthreads();
    bf16x4 pk[2][8];
#pragma unroll
    for (int t = 0; t < 8; ++t) {
      const __bf16* kr = Ks + (t * 16 + l15) * 64;
      bf16x8 kf0 = *(const bf16x8*)(kr + kfs0);
      bf16x8 kf1 = *(const bf16x8*)(kr + kfs1);
      f32x4 z0 = {}, z1 = {};
      z0 = MFMA16(kf0, qf[0][0], z0);
      z0 = MFMA16(kf1, qf[0][1], z0);
      z1 = MFMA16(kf0, qf[1][0], z1);
      z1 = MFMA16(kf1, qf[1][1], z1);
      float p00 = exp2f(z0[0]), p01 = exp2f(z0[1]), p02 = exp2f(z0[2]), p03 = exp2f(z0[3]);
      float p10 = exp2f(z1[0]), p11 = exp2f(z1[1]), p12 = exp2f(z1[2]), p13 = exp2f(z1[3]);
      rs0 += (p00 + p01) + (p02 + p03);
      rs1 += (p10 + p11) + (p12 + p13);
      pk[0][t] = (bf16x4){(__bf16)p00, (__bf16)p01, (__bf16)p02, (__bf16)p03};
      pk[1][t] = (bf16x4){(__bf16)p10, (__bf16)p11, (__bf16)p12, (__bf16)p13};
    }
#pragma unroll
    for (int Q = 0; Q < 4; ++Q) {
#pragma unroll
      for (int f = 0; f < 2; ++f)
#pragma unroll
        for (int tl = 0; tl < 2; ++tl) {
          int g = (2 * tl + (quad >> 1)) ^ (l15 & 3);
          *(bf16x4*)(pw + (f * 16 + l15) * 32 + g * 8 + (quad & 1) * 4) = pk[f][2 * Q + tl];
        }
      bf16x8 pf0 = *(const bf16x8*)(pw + l15 * 32 + psw * 8);
      bf16x8 pf1 = *(const bf16x8*)(pw + (16 + l15) * 32 + psw * 8);
#pragma unroll
      for (int dt = 0; dt < 4; ++dt) {
        bf16x8 vf = *(const bf16x8*)(Vs + (dt * 16 + l15) * 128 + (((Q * 4 + quad) ^ l15) * 8));
        o[0][dt] = MFMA16(pf0, vf, o[0][dt]);
        o[1][dt] = MFMA16(pf1, vf, o[1][dt]);
      }
    }
  }
  rs0 += __shfl_xor(rs0, 16); rs0 += __shfl_xor(rs0, 32);
  rs1 += __shfl_xor(rs1, 16); rs1 += __shfl_xor(rs1, 32);
  const int b = bh >> 4, h = bh & 15;
  const int qbase = quad << 4;
#pragma unroll
  for (int r = 0; r < 4; ++r) {
    int src = qbase | (quad * 4 + r);
    float inv0 = 1.0f / __shfl(rs0, src);
    float inv1 = 1.0f / __shfl(rs1, src);
    long row0 = b * 1024 + qrow + quad * 4 + r;
    long row1 = row0 + 16;
#pragma unroll
    for (int dt = 0; dt < 4; ++dt) {
      ao[row0 * 1024 + h * 64 + dt * 16 + l15] = (__bf16)(o[0][dt][r] * inv0);
      ao[row1 * 1024 + h * 64 + dt * 16 + l15] = (__bf16)(o[1][dt][r] * inv1);
    }
  }
}

// ---------------- launch ----------------
extern "C" void kernel_launch(void* const* d_in, const int* in_sizes, int n_in,
                              void* d_out, int out_size, void* d_ws, size_t ws_size,
                              hipStream_t stream) {
  const float* x = (const float*)d_in[0];      // [8192,1024]
  const float* w_qkv = (const float*)d_in[1];  // [1024,3072]
  const float* w_out = (const float*)d_in[2];  // [1024,1024]
  const float* b_out = (const float*)d_in[3];  // [1024]
  float* out = (float*)d_out;

  char* ws = (char*)d_ws;
  __bf16* xb    = (__bf16*)(ws);                 // 16 MiB
  __bf16* wqkvt = (__bf16*)(ws + 16777216);      // 6 MiB
  __bf16* woutt = (__bf16*)(ws + 23068672);      // 2 MiB
  __bf16* qw    = (__bf16*)(ws + 25165824);
  __bf16* kw    = (__bf16*)(ws + 41943040);
  __bf16* vw    = (__bf16*)(ws + 58720256);      // end = 75497472
  __bf16* ao    = xb;  // alias: xb dead after QKV GEMM

  cast_x_kernel<<<8192, 256, 0, stream>>>(x, xb);
  transpose_cast_kernel<<<dim3(96, 32), dim3(32, 8), 0, stream>>>(w_qkv, wqkvt, 1024, 3072);
  transpose_cast_kernel<<<dim3(32, 32), dim3(32, 8), 0, stream>>>(w_out, woutt, 1024, 1024);
  gemm_bt_kernel<<<1536, 256, 0, stream>>>(xb, wqkvt, 0, 3, qw, kw, vw, nullptr, nullptr);
  attn_kernel<<<1024, 256, 0, stream>>>(qw, kw, vw, ao);
  gemm_bt_kernel<<<512, 256, 0, stream>>>(ao, woutt, 1, 1, nullptr, nullptr, nullptr, out, b_out);
}